// Round 10
// baseline (521.318 us; speedup 1.0000x reference)
//
#include <hip/hip_runtime.h>

#define BB 16
#define NN 4096
#define CC 128
#define PP 1024
#define SS 32
#define MM (BB*PP*SS)       // 524288
#define NBLK 8192           // stat-partial stride
#define OFF_NF 49152        // 16*1024*3
#define OFF_SI 4243456      // 49152 + 16*256*1024

typedef unsigned short u16;
typedef unsigned int u32;
typedef __attribute__((ext_vector_type(8))) short short8v;
typedef __attribute__((ext_vector_type(4))) float f32x4;

__device__ __forceinline__ float b2f(u16 u) {
    union { float f; unsigned i; } x; x.i = ((unsigned)u) << 16; return x.f;
}
__device__ __forceinline__ u16 f2b(float f) {   // RTNE bf16
    union { float f; unsigned i; } x; x.f = f;
    unsigned r = x.i + 0x7fffu + ((x.i >> 16) & 1u);
    return (u16)(r >> 16);
}
__device__ __forceinline__ float2 act2(u32 u, float2 s0, float2 s1) {
    union { float f; unsigned i; } a, b;
    a.i = u << 16; b.i = u & 0xffff0000u;
    return make_float2(fmaxf(fmaf(s0.x, a.f, s0.y), 0.f),
                       fmaxf(fmaf(s1.x, b.f, s1.y), 0.f));
}
__device__ __forceinline__ u32 packbf(float flo, float fhi) {
    union { float f; unsigned i; } x0, x1; x0.f = flo; x1.f = fhi;
    return __builtin_amdgcn_perm(x1.i, x0.i, 0x07060302u);
}
__device__ __forceinline__ u32 packbf_rtne(float flo, float fhi) {
    union { float f; unsigned i; } x0, x1; x0.f = flo; x1.f = fhi;
    u32 r0 = x0.i + 0x7fffu + ((x0.i >> 16) & 1u);
    u32 r1 = x1.i + 0x7fffu + ((x1.i >> 16) & 1u);
    return __builtin_amdgcn_perm(r1, r0, 0x07060302u);
}
__device__ __forceinline__ u32 act_pack(u32 u, float2 s0, float2 s1) {
    float2 f = act2(u, s0, s1);
    return packbf(f.x, f.y);
}
__device__ __forceinline__ short8v as_s8(uint4 v) {
    union { uint4 u; short8v s; } x; x.u = v; return x.s;
}

#define MFMA16(a,b,c) __builtin_amdgcn_mfma_f32_16x16x32_bf16(a,b,c,0,0,0)

// ---------------------------------------------------------------------------
// k_init: new_xyz + sample_idxs + w0t/w0b/w1b/w2b + zero cntw (gather weights)
// ---------------------------------------------------------------------------
__global__ void k_init(const float* __restrict__ xyz, const float* __restrict__ w0,
                       const float* __restrict__ w1, const float* __restrict__ w2,
                       float* __restrict__ out, float* __restrict__ w0t,
                       u16* __restrict__ w0b, u16* __restrict__ w1b,
                       u16* __restrict__ w2b, float* __restrict__ cntw) {
    int i = blockIdx.x * 256 + threadIdx.x;
    if (i < 49152) {
        int b = i / 3072, r = i % 3072;
        out[i] = xyz[b * 12288 + r];
        return;
    }
    int j = i - 49152;
    if (j < 16384) { out[OFF_SI + j] = (float)(j & 1023); return; }
    int e = j - 16384;
    if (e < 384) { w0t[e] = w0[(e & 127) * 131 + (e >> 7)]; return; }
    int f = e - 384;
    if (f < 16384) { w0b[f] = f2b(w0[(f >> 7) * 131 + 3 + (f & 127)]); return; }
    int h = f - 16384;
    if (h < 16384) { w1b[h] = f2b(w1[h]); return; }
    int k2 = h - 16384;
    if (k2 < 32768) { w2b[k2] = f2b(w2[k2]); return; }
    int z = k2 - 32768;
    if (z < 262144) { cntw[z] = 0.f; }
}

// ---------------------------------------------------------------------------
// k_ballquery: wave-per-center ballot scan + per-point gather-weight scatter
// (cnt, Σrelx, Σrely, Σrelz via atomics over 65536 addresses) + 9 rel-moment
// scalars as per-wave partials (no atomic hotspot).
// ---------------------------------------------------------------------------
__global__ __launch_bounds__(256) void k_ballquery(const float* __restrict__ xyz,
                                                   int* __restrict__ oidx,
                                                   float* __restrict__ relx,
                                                   float* __restrict__ rely,
                                                   float* __restrict__ relz,
                                                   float* __restrict__ cntw,
                                                   float* __restrict__ rpart) {
    __shared__ float sx[NN], sy[NN], sz[NN];
    int t = threadIdx.x, w = t >> 6, lane = t & 63;
    int b = blockIdx.x >> 8;
    int p = (blockIdx.x & 255) * 4 + w;
    const float* xb = xyz + (long)b * NN * 3;
    for (int i = t; i < NN; i += 256) {
        sx[i] = xb[3 * i]; sy[i] = xb[3 * i + 1]; sz[i] = xb[3 * i + 2];
    }
    __syncthreads();
    float* cntp = cntw;
    float* wxp = cntw + 65536;
    float* wyp = cntw + 2 * 65536;
    float* wzp = cntw + 3 * 65536;
    const float R2 = (float)(0.4 * 0.4);
    float cx = sx[p], cy = sy[p], cz = sz[p];
    int o = (b * PP + p) * SS;
    int cnt = 0, firstn = 0;
    float fdx = 0.f, fdy = 0.f, fdz = 0.f;
    float srx = 0.f, sry = 0.f, srz = 0.f;
    float sxx = 0.f, syy = 0.f, szz = 0.f, sxy = 0.f, sxz = 0.f, syz = 0.f;
    for (int c = 0; c < 64 && cnt < 32; ++c) {
        int n = c * 64 + lane;
        float dx = __fsub_rn(sx[n], cx);
        float dy = __fsub_rn(sy[n], cy);
        float dz = __fsub_rn(sz[n], cz);
        float d2 = __fadd_rn(__fadd_rn(__fmul_rn(dx, dx), __fmul_rn(dy, dy)),
                             __fmul_rn(dz, dz));
        bool hit = d2 < R2;
        unsigned long long mask = __ballot(hit);
        if (mask) {
            if (cnt == 0) {
                int fl = __ffsll(mask) - 1;
                firstn = c * 64 + fl;
                fdx = __shfl(dx, fl); fdy = __shfl(dy, fl); fdz = __shfl(dz, fl);
            }
            int pos = cnt + __popcll(mask & ((1ull << lane) - 1ull));
            if (hit && pos < 32) {
                oidx[o + pos] = n;
                relx[o + pos] = dx; rely[o + pos] = dy; relz[o + pos] = dz;
                int gn = b * NN + n;
                atomicAdd(&cntp[gn], 1.f);
                atomicAdd(&wxp[gn], dx); atomicAdd(&wyp[gn], dy); atomicAdd(&wzp[gn], dz);
                srx += dx; sry += dy; srz += dz;
                sxx = fmaf(dx, dx, sxx); syy = fmaf(dy, dy, syy); szz = fmaf(dz, dz, szz);
                sxy = fmaf(dx, dy, sxy); sxz = fmaf(dx, dz, sxz); syz = fmaf(dy, dz, syz);
            }
            cnt += __popcll(mask);
        }
    }
    int stored = cnt < 32 ? cnt : 32;
    if (lane < 32 && lane >= stored) {
        oidx[o + lane] = firstn;
        relx[o + lane] = fdx; rely[o + lane] = fdy; relz[o + lane] = fdz;
    }
    if (lane == 0 && stored < 32) {
        float pad = (float)(32 - stored);
        int gn = b * NN + firstn;
        atomicAdd(&cntp[gn], pad);
        atomicAdd(&wxp[gn], pad * fdx); atomicAdd(&wyp[gn], pad * fdy);
        atomicAdd(&wzp[gn], pad * fdz);
        srx += pad * fdx; sry += pad * fdy; srz += pad * fdz;
        sxx += pad * fdx * fdx; syy += pad * fdy * fdy; szz += pad * fdz * fdz;
        sxy += pad * fdx * fdy; sxz += pad * fdx * fdz; syz += pad * fdy * fdz;
    }
#pragma unroll
    for (int d = 1; d < 64; d <<= 1) {
        srx += __shfl_xor(srx, d); sry += __shfl_xor(sry, d); srz += __shfl_xor(srz, d);
        sxx += __shfl_xor(sxx, d); syy += __shfl_xor(syy, d); szz += __shfl_xor(szz, d);
        sxy += __shfl_xor(sxy, d); sxz += __shfl_xor(sxz, d); syz += __shfl_xor(syz, d);
    }
    if (lane == 0) {
        int wid = blockIdx.x * 4 + w;
        rpart[0 * 16384 + wid] = srx; rpart[1 * 16384 + wid] = sry;
        rpart[2 * 16384 + wid] = srz; rpart[3 * 16384 + wid] = sxx;
        rpart[4 * 16384 + wid] = syy; rpart[5 * 16384 + wid] = szz;
        rpart[6 * 16384 + wid] = sxy; rpart[7 * 16384 + wid] = sxz;
        rpart[8 * 16384 + wid] = syz;
    }
}

// ---------------------------------------------------------------------------
// k_f1: F1[n][co] = sum_ci feat[ci][n] * w0[co][3+ci] via MFMA (fp32 out).
// ---------------------------------------------------------------------------
__global__ __launch_bounds__(256) void k_f1(const float* __restrict__ feat,
                                            const u16* __restrict__ w0b,
                                            float* __restrict__ F1) {
    __shared__ uint4 abuf[64 * 17];
    int t = threadIdx.x;
    int w = t >> 6, lane = t & 63, q = lane >> 4, l16 = lane & 15;
    int cb = (w & 1) * 64, wm0 = (w >> 1) * 32;
    short8v bf[4][4];
#pragma unroll
    for (int ct = 0; ct < 4; ++ct)
#pragma unroll
        for (int k0 = 0; k0 < 4; ++k0)
            bf[ct][k0] = *(const short8v*)(w0b + (cb + ct * 16 + l16) * 128 + k0 * 32 + q * 8);
    int nl = t & 63, cg = t >> 6;
    const float* fcol = feat + (long)(blockIdx.x >> 6) * (128 * 4096)
                             + (long)(blockIdx.x & 63) * 64 + nl;
#pragma unroll
    for (int pp = 0; pp < 4; ++pp) {
        int oct = cg + 4 * pp;
        float v[8];
#pragma unroll
        for (int r = 0; r < 8; ++r) v[r] = fcol[(long)(oct * 8 + r) * 4096];
        uint4 ov;
        ov.x = packbf_rtne(v[0], v[1]); ov.y = packbf_rtne(v[2], v[3]);
        ov.z = packbf_rtne(v[4], v[5]); ov.w = packbf_rtne(v[6], v[7]);
        abuf[nl * 17 + ((oct + nl) & 15)] = ov;
    }
    __syncthreads();
    f32x4 acc[2][4];
#pragma unroll
    for (int mt = 0; mt < 2; ++mt)
#pragma unroll
        for (int ct = 0; ct < 4; ++ct) acc[mt][ct] = (f32x4){0.f, 0.f, 0.f, 0.f};
#pragma unroll
    for (int mt = 0; mt < 2; ++mt) {
        int row = wm0 + mt * 16 + l16;
#pragma unroll
        for (int k0 = 0; k0 < 4; ++k0) {
            uint4 vv = abuf[row * 17 + ((k0 * 4 + q + row) & 15)];
            short8v af = as_s8(vv);
#pragma unroll
            for (int ct = 0; ct < 4; ++ct)
                acc[mt][ct] = MFMA16(af, bf[ct][k0], acc[mt][ct]);
        }
    }
    long nbase = (long)blockIdx.x * 64;
#pragma unroll
    for (int mt = 0; mt < 2; ++mt)
#pragma unroll
        for (int ct = 0; ct < 4; ++ct)
#pragma unroll
            for (int r = 0; r < 4; ++r)
                F1[(nbase + wm0 + mt * 16 + q * 4 + r) * 128 + cb + ct * 16 + l16]
                    = acc[mt][ct][r];
}

// ---------------------------------------------------------------------------
// k_st0part: weighted F1 reductions per channel: Σcnt·F1, Σcnt·F1², Σwx·F1,
// Σwy·F1, Σwz·F1. 256 blocks x 256 rows. Output p5[5][128][256].
// ---------------------------------------------------------------------------
__global__ __launch_bounds__(256) void k_st0part(const float* __restrict__ F1,
                                                 const float* __restrict__ cntw,
                                                 float* __restrict__ p5) {
    int t = threadIdx.x, w = t >> 6, lane = t & 63;
    int c0 = 2 * lane;
    const float* cntp = cntw;
    const float* wxp = cntw + 65536;
    const float* wyp = cntw + 2 * 65536;
    const float* wzp = cntw + 3 * 65536;
    float p1a = 0.f, p1b = 0.f, p2a = 0.f, p2b = 0.f;
    float pxa = 0.f, pxb = 0.f, pya = 0.f, pyb = 0.f, pza = 0.f, pzb = 0.f;
    int base = blockIdx.x * 256 + w;
    for (int i = 0; i < 64; ++i) {
        int n = base + 4 * i;
        float cn = cntp[n], wxn = wxp[n], wyn = wyp[n], wzn = wzp[n];
        float2 f = *(const float2*)(F1 + (long)n * 128 + c0);
        p1a = fmaf(cn, f.x, p1a);        p1b = fmaf(cn, f.y, p1b);
        p2a = fmaf(cn * f.x, f.x, p2a);  p2b = fmaf(cn * f.y, f.y, p2b);
        pxa = fmaf(wxn, f.x, pxa);       pxb = fmaf(wxn, f.y, pxb);
        pya = fmaf(wyn, f.x, pya);       pyb = fmaf(wyn, f.y, pyb);
        pza = fmaf(wzn, f.x, pza);       pzb = fmaf(wzn, f.y, pzb);
    }
    __shared__ float red[5][128][4];
    red[0][c0][w] = p1a; red[0][c0 + 1][w] = p1b;
    red[1][c0][w] = p2a; red[1][c0 + 1][w] = p2b;
    red[2][c0][w] = pxa; red[2][c0 + 1][w] = pxb;
    red[3][c0][w] = pya; red[3][c0 + 1][w] = pyb;
    red[4][c0][w] = pza; red[4][c0 + 1][w] = pzb;
    __syncthreads();
    if (t < 128) {
#pragma unroll
        for (int k = 0; k < 5; ++k)
            p5[k * 32768 + t * 256 + blockIdx.x]
                = red[k][t][0] + red[k][t][1] + red[k][t][2] + red[k][t][3];
    }
}

// ---------------------------------------------------------------------------
// k_st0fin: combine p5 partials + 9 rel-moment scalars -> st0 (scale, shift).
// S1 = P1 + w.SR ; S2 = P2 + 2 w.PA + wGw (rel second moments).
// ---------------------------------------------------------------------------
__global__ void k_st0fin(const float* __restrict__ p5, const float* __restrict__ rpart,
                         const float* __restrict__ w0t, const float* __restrict__ g0,
                         const float* __restrict__ be0, float* __restrict__ st0) {
    __shared__ float sred[9][16];
    __shared__ float scal[9];
    int t = threadIdx.x;
    if (t < 144) {
        int k = t >> 4, s = t & 15;
        const float* rp = rpart + k * 16384 + s * 1024;
        float a = 0.f;
        for (int j = 0; j < 1024; ++j) a += rp[j];
        sred[k][s] = a;
    }
    __syncthreads();
    if (t < 9) {
        float a = 0.f;
        for (int s = 0; s < 16; ++s) a += sred[t][s];
        scal[t] = a;
    }
    __syncthreads();
    if (t < 128) {
        float P1 = 0.f, P2 = 0.f, PX = 0.f, PY = 0.f, PZ = 0.f;
        const float* b0 = p5 + t * 256;
        for (int j = 0; j < 256; ++j) {
            P1 += b0[j];
            P2 += b0[32768 + j];
            PX += b0[2 * 32768 + j];
            PY += b0[3 * 32768 + j];
            PZ += b0[4 * 32768 + j];
        }
        float wx = w0t[t], wy = w0t[128 + t], wz = w0t[256 + t];
        float S1 = P1 + wx * scal[0] + wy * scal[1] + wz * scal[2];
        float S2 = P2 + 2.f * (wx * PX + wy * PY + wz * PZ)
                 + wx * wx * scal[3] + wy * wy * scal[4] + wz * wz * scal[5]
                 + 2.f * (wx * wy * scal[6] + wx * wz * scal[7] + wy * wz * scal[8]);
        const float inv = 1.f / (float)MM;
        float mean = S1 * inv;
        float var = S2 * inv - mean * mean;
        float sc = g0[t] * rsqrtf(var + 1e-5f);
        st0[2 * t] = sc;
        st0[2 * t + 1] = fmaf(-mean, sc, be0[t]);
    }
}

// ---------------------------------------------------------------------------
// k_conv1f: FUSED y0-gather + conv1. Staging computes y0 = F1[gather] + rel.w0
// on the fly (no y0 buffer), applies act0, packs to bf16 LDS tile; then
// W1 MFMA -> y1 + layer-1 stat partials. Block = 512m x 128co.
// ---------------------------------------------------------------------------
__global__ __launch_bounds__(256, 2) void k_conv1f(const float* __restrict__ F1,
                                                   const int* __restrict__ idx,
                                                   const float* __restrict__ relx,
                                                   const float* __restrict__ rely,
                                                   const float* __restrict__ relz,
                                                   const float* __restrict__ w0t,
                                                   const u16* __restrict__ w1b,
                                                   const float* __restrict__ st0,
                                                   u16* __restrict__ y1,
                                                   float* __restrict__ part,
                                                   float* __restrict__ partq) {
    __shared__ uint4 abuf[2][64 * 17];
    __shared__ float2 sst[128];
    __shared__ float sredA[4][64], sredB[4][64];
    int t = threadIdx.x;
    if (t < 128) sst[t] = ((const float2*)st0)[t];
    int w = t >> 6, lane = t & 63, q = lane >> 4, l16 = lane & 15;
    int wm0 = (w >> 1) * 32, cb = (w & 1) * 64;
    short8v bf[4][4];
#pragma unroll
    for (int ct = 0; ct < 4; ++ct)
#pragma unroll
        for (int k0 = 0; k0 < 4; ++k0)
            bf[ct][k0] = *(const short8v*)(w1b + (cb + ct * 16 + l16) * 128 + k0 * 32 + q * 8);
    int sr = t >> 4, sc16 = t & 15;
    float wxr[8], wyr[8], wzr[8];
#pragma unroll
    for (int j = 0; j < 8; ++j) {
        wxr[j] = w0t[sc16 * 8 + j];
        wyr[j] = w0t[128 + sc16 * 8 + j];
        wzr[j] = w0t[256 + sc16 * 8 + j];
    }
    __syncthreads();
    long m0b = (long)blockIdx.x * 512;
    float s1[4] = {0.f, 0.f, 0.f, 0.f}, s2[4] = {0.f, 0.f, 0.f, 0.f};
    for (int c = 0; c < 8; ++c) {
        long m0 = m0b + c * 64;
        uint4* ab = abuf[c & 1];
#pragma unroll
        for (int p = 0; p < 4; ++p) {
            int r = p * 16 + sr;
            long m = m0 + r;
            int id = idx[m];
            int b = (int)(m >> 15);
            float rx = relx[m], ry = rely[m], rz = relz[m];
            const float* fr = F1 + ((long)(b * NN + id)) * 128 + sc16 * 8;
            float4 fa = *(const float4*)fr;
            float4 fb = *(const float4*)(fr + 4);
            float v[8] = {fa.x, fa.y, fa.z, fa.w, fb.x, fb.y, fb.z, fb.w};
            u32 od[4];
#pragma unroll
            for (int j = 0; j < 4; ++j) {
                float y0a = fmaf(wxr[2 * j], rx, fmaf(wyr[2 * j], ry,
                             fmaf(wzr[2 * j], rz, v[2 * j])));
                float y0b = fmaf(wxr[2 * j + 1], rx, fmaf(wyr[2 * j + 1], ry,
                             fmaf(wzr[2 * j + 1], rz, v[2 * j + 1])));
                float2 ss0 = sst[sc16 * 8 + 2 * j], ss1 = sst[sc16 * 8 + 2 * j + 1];
                float a0 = fmaxf(fmaf(ss0.x, y0a, ss0.y), 0.f);
                float a1 = fmaxf(fmaf(ss1.x, y0b, ss1.y), 0.f);
                od[j] = packbf(a0, a1);
            }
            ab[r * 17 + ((sc16 + r) & 15)] = make_uint4(od[0], od[1], od[2], od[3]);
        }
        __syncthreads();
        f32x4 acc[2][4];
#pragma unroll
        for (int mt = 0; mt < 2; ++mt)
#pragma unroll
            for (int ct = 0; ct < 4; ++ct) acc[mt][ct] = (f32x4){0.f, 0.f, 0.f, 0.f};
#pragma unroll
        for (int mt = 0; mt < 2; ++mt) {
            int row = wm0 + mt * 16 + l16;
#pragma unroll
            for (int k0 = 0; k0 < 4; ++k0) {
                uint4 v = ab[row * 17 + ((k0 * 4 + q + row) & 15)];
                short8v af = as_s8(v);
#pragma unroll
                for (int ct = 0; ct < 4; ++ct)
                    acc[mt][ct] = MFMA16(af, bf[ct][k0], acc[mt][ct]);
            }
        }
#pragma unroll
        for (int mt = 0; mt < 2; ++mt)
#pragma unroll
            for (int ct = 0; ct < 4; ++ct)
#pragma unroll
                for (int r = 0; r < 4; ++r) {
                    float v = acc[mt][ct][r];
                    y1[(m0 + wm0 + mt * 16 + q * 4 + r) * 128 + cb + ct * 16 + l16] = f2b(v);
                    s1[ct] += v; s2[ct] = fmaf(v, v, s2[ct]);
                }
    }
#pragma unroll
    for (int ct = 0; ct < 4; ++ct) {
        float a = s1[ct], b = s2[ct];
        a += __shfl_xor(a, 16); a += __shfl_xor(a, 32);
        b += __shfl_xor(b, 16); b += __shfl_xor(b, 32);
        if (lane < 16) { sredA[w][ct * 16 + l16] = a; sredB[w][ct * 16 + l16] = b; }
    }
    __syncthreads();
    if (t < 128) {
        int h = t >> 6, cl = t & 63;
        part [(long)t * NBLK + blockIdx.x] = sredA[h][cl] + sredA[h + 2][cl];
        partq[(long)t * NBLK + blockIdx.x] = sredB[h][cl] + sredB[h + 2][cl];
    }
}

// ---------------------------------------------------------------------------
// k_bnfin: reduce per-channel partials -> (scale, shift). grid = #channels.
// ---------------------------------------------------------------------------
__global__ void k_bnfin(const float* __restrict__ part, const float* __restrict__ partq,
                        const float* __restrict__ g, const float* __restrict__ beta,
                        float* __restrict__ st, int nblk) {
    int co = blockIdx.x, t = threadIdx.x;
    const float* p1 = part + (long)co * NBLK;
    const float* p2 = partq + (long)co * NBLK;
    float s1 = 0.f, s2 = 0.f;
    for (int j = t; j < nblk; j += 256) { s1 += p1[j]; s2 += p2[j]; }
    __shared__ float r1[256], r2[256];
    r1[t] = s1; r2[t] = s2; __syncthreads();
    for (int off = 128; off > 0; off >>= 1) {
        if (t < off) { r1[t] += r1[t + off]; r2[t] += r2[t + off]; }
        __syncthreads();
    }
    if (t == 0) {
        const float inv = 1.f / (float)MM;
        float mean = r1[0] * inv;
        float var = r2[0] * inv - mean * mean;
        float sc = g[co] * rsqrtf(var + 1e-5f);
        st[2 * co] = sc;
        st[2 * co + 1] = fmaf(-mean, sc, beta[co]);
    }
}

// ---------------------------------------------------------------------------
// k_conv2pool: round-9 verified (68us): B resident bf[4][4], wave 64m x 64co,
// rotation swizzle, fused BN2 stat partials, raw min/max per 32-row group.
// ---------------------------------------------------------------------------
__global__ __launch_bounds__(256) void k_conv2pool(const u16* __restrict__ y1,
                                                   const u16* __restrict__ w2b,
                                                   const float* __restrict__ st1,
                                                   float* __restrict__ rawmax,
                                                   float* __restrict__ rawmin,
                                                   float* __restrict__ part,
                                                   float* __restrict__ partq) {
    __shared__ uint4 abuf[2][64 * 17];
    __shared__ float2 sst[128];
    __shared__ float sredA[4][64], sredB[4][64];
    int t = threadIdx.x;
    if (t < 128) sst[t] = ((const float2*)st1)[t];
    int w = t >> 6, lane = t & 63, q = lane >> 4, l16 = lane & 15;
    int cb = w * 64;
    short8v bf[4][4];
#pragma unroll
    for (int ct = 0; ct < 4; ++ct)
#pragma unroll
        for (int k0 = 0; k0 < 4; ++k0)
            bf[ct][k0] = *(const short8v*)(w2b + (cb + ct * 16 + l16) * 128 + k0 * 32 + q * 8);
    __syncthreads();
    long m0b = (long)blockIdx.x * 512;
    int sr = t >> 4, sc16 = t & 15;
    float s1[4] = {0.f, 0.f, 0.f, 0.f}, s2[4] = {0.f, 0.f, 0.f, 0.f};
    for (int c = 0; c < 8; ++c) {
        long m0 = m0b + c * 64;
        uint4* ab = abuf[c & 1];
        const uint4* gsrc = (const uint4*)y1;
#pragma unroll
        for (int p = 0; p < 4; ++p) {
            int r = p * 16 + sr;
            uint4 d = gsrc[(m0 + r) * 16 + sc16];
            uint4 o;
            o.x = act_pack(d.x, sst[sc16 * 8 + 0], sst[sc16 * 8 + 1]);
            o.y = act_pack(d.y, sst[sc16 * 8 + 2], sst[sc16 * 8 + 3]);
            o.z = act_pack(d.z, sst[sc16 * 8 + 4], sst[sc16 * 8 + 5]);
            o.w = act_pack(d.w, sst[sc16 * 8 + 6], sst[sc16 * 8 + 7]);
            ab[r * 17 + ((sc16 + r) & 15)] = o;
        }
        __syncthreads();
        f32x4 acc[4][4];
#pragma unroll
        for (int mt = 0; mt < 4; ++mt)
#pragma unroll
            for (int ct = 0; ct < 4; ++ct) acc[mt][ct] = (f32x4){0.f, 0.f, 0.f, 0.f};
#pragma unroll
        for (int mt = 0; mt < 4; ++mt) {
            int row = mt * 16 + l16;
#pragma unroll
            for (int k0 = 0; k0 < 4; ++k0) {
                uint4 v = ab[row * 17 + ((k0 * 4 + q + row) & 15)];
                short8v af = as_s8(v);
#pragma unroll
                for (int ct = 0; ct < 4; ++ct)
                    acc[mt][ct] = MFMA16(af, bf[ct][k0], acc[mt][ct]);
            }
        }
#pragma unroll
        for (int ct = 0; ct < 4; ++ct) {
#pragma unroll
            for (int g = 0; g < 2; ++g) {
                f32x4 a0 = acc[2 * g][ct], a1 = acc[2 * g + 1][ct];
                s1[ct] += a0[0] + a0[1] + a0[2] + a0[3] + a1[0] + a1[1] + a1[2] + a1[3];
                s2[ct] = fmaf(a0[0], a0[0], s2[ct]); s2[ct] = fmaf(a0[1], a0[1], s2[ct]);
                s2[ct] = fmaf(a0[2], a0[2], s2[ct]); s2[ct] = fmaf(a0[3], a0[3], s2[ct]);
                s2[ct] = fmaf(a1[0], a1[0], s2[ct]); s2[ct] = fmaf(a1[1], a1[1], s2[ct]);
                s2[ct] = fmaf(a1[2], a1[2], s2[ct]); s2[ct] = fmaf(a1[3], a1[3], s2[ct]);
                float mx = fmaxf(fmaxf(fmaxf(a0[0], a0[1]), fmaxf(a0[2], a0[3])),
                                 fmaxf(fmaxf(a1[0], a1[1]), fmaxf(a1[2], a1[3])));
                float mn = fminf(fminf(fminf(a0[0], a0[1]), fminf(a0[2], a0[3])),
                                 fminf(fminf(a1[0], a1[1]), fminf(a1[2], a1[3])));
                mx = fmaxf(mx, __shfl_xor(mx, 16)); mx = fmaxf(mx, __shfl_xor(mx, 32));
                mn = fminf(mn, __shfl_xor(mn, 16)); mn = fminf(mn, __shfl_xor(mn, 32));
                if (lane < 16) {
                    long bp = (long)blockIdx.x * 16 + c * 2 + g;
                    rawmax[bp * 256 + cb + ct * 16 + l16] = mx;
                    rawmin[bp * 256 + cb + ct * 16 + l16] = mn;
                }
            }
        }
    }
#pragma unroll
    for (int ct = 0; ct < 4; ++ct) {
        float a = s1[ct], b = s2[ct];
        a += __shfl_xor(a, 16); a += __shfl_xor(a, 32);
        b += __shfl_xor(b, 16); b += __shfl_xor(b, 32);
        if (lane < 16) { sredA[w][ct * 16 + l16] = a; sredB[w][ct * 16 + l16] = b; }
    }
    __syncthreads();
    {
        part [(long)t * NBLK + blockIdx.x] = sredA[t >> 6][t & 63];
        partq[(long)t * NBLK + blockIdx.x] = sredB[t >> 6][t & 63];
    }
}

// ---------------------------------------------------------------------------
// k_final: z = relu(sc>0 ? sc*max+sh : sc*min+sh); transpose to out[b][co][p].
// ---------------------------------------------------------------------------
__global__ void k_final(const float* __restrict__ rawmax, const float* __restrict__ rawmin,
                        const float* __restrict__ st2, float* __restrict__ out) {
    __shared__ float tile[32][33];
    int b = blockIdx.x >> 8;
    int p0 = ((blockIdx.x >> 3) & 31) * 32;
    int c0 = (blockIdx.x & 7) * 32;
    int j = threadIdx.x & 31, i0 = threadIdx.x >> 5;
    float sc = st2[2 * (c0 + j)], sh = st2[2 * (c0 + j) + 1];
#pragma unroll
    for (int rr = 0; rr < 4; ++rr) {
        int i = i0 + rr * 8;
        long idx = ((long)(b * 1024 + p0 + i)) * 256 + c0 + j;
        float v = sc > 0.f ? fmaf(sc, rawmax[idx], sh) : fmaf(sc, rawmin[idx], sh);
        tile[i][j] = fmaxf(v, 0.f);
    }
    __syncthreads();
#pragma unroll
    for (int rr = 0; rr < 4; ++rr) {
        int i = i0 + rr * 8;
        out[OFF_NF + (long)b * 262144 + (c0 + i) * 1024 + p0 + j] = tile[j][i];
    }
}

// ---------------------------------------------------------------------------
extern "C" void kernel_launch(void* const* d_in, const int* in_sizes, int n_in,
                              void* d_out, int out_size, void* d_ws, size_t ws_size,
                              hipStream_t stream) {
    (void)in_sizes; (void)n_in; (void)out_size; (void)ws_size;
    const float* xyz  = (const float*)d_in[0];
    const float* feat = (const float*)d_in[1];
    const float* w0   = (const float*)d_in[3];
    const float* g0   = (const float*)d_in[5];
    const float* be0  = (const float*)d_in[6];
    const float* w1   = (const float*)d_in[7];
    const float* g1   = (const float*)d_in[9];
    const float* be1  = (const float*)d_in[10];
    const float* w2   = (const float*)d_in[11];
    const float* g2   = (const float*)d_in[13];
    const float* be2  = (const float*)d_in[14];
    float* out = (float*)d_out;

    char* ws = (char*)d_ws;
    size_t off = 0;
    auto alloc = [&](size_t bytes) -> void* {
        void* p = ws + off;
        off = (off + bytes + 4095) & ~(size_t)4095;
        return p;
    };
    int*   idx    = (int*)  alloc((size_t)MM * 4);            // 2 MB
    float* relx   = (float*)alloc((size_t)MM * 4);            // 2 MB
    float* rely   = (float*)alloc((size_t)MM * 4);            // 2 MB
    float* relz   = (float*)alloc((size_t)MM * 4);            // 2 MB
    float* w0t    = (float*)alloc(3 * 128 * 4);
    u16*   w0b    = (u16*)  alloc(128 * 128 * 2);
    u16*   w1b    = (u16*)  alloc(128 * 128 * 2);
    u16*   w2b    = (u16*)  alloc(256 * 128 * 2);
    float* st0    = (float*)alloc(128 * 2 * 4);
    float* st1    = (float*)alloc(128 * 2 * 4);
    float* st2    = (float*)alloc(256 * 2 * 4);
    float* cntw   = (float*)alloc((size_t)4 * 65536 * 4);     // 1 MB
    float* rpart  = (float*)alloc((size_t)9 * 16384 * 4);     // 576 KB
    float* p5     = (float*)alloc((size_t)5 * 128 * 256 * 4); // 640 KB
    float* part   = (float*)alloc((size_t)256 * NBLK * 4);    // 8 MB
    float* partq  = (float*)alloc((size_t)256 * NBLK * 4);    // 8 MB
    float* F1     = (float*)alloc((size_t)BB * NN * 128 * 4); // 33.5 MB
    float* rawmax = (float*)alloc((size_t)BB * PP * 256 * 4); // 16 MB
    float* rawmin = (float*)alloc((size_t)BB * PP * 256 * 4); // 16 MB
    u16*   bufA   = (u16*)  alloc((size_t)MM * 128 * 2);      // 134 MB (y1)
    // total ~226 MB

    k_init<<<1538, 256, 0, stream>>>(xyz, w0, w1, w2, out, w0t, w0b, w1b, w2b, cntw);
    k_ballquery<<<4096, 256, 0, stream>>>(xyz, idx, relx, rely, relz, cntw, rpart);
    k_f1<<<1024, 256, 0, stream>>>(feat, w0b, F1);
    k_st0part<<<256, 256, 0, stream>>>(F1, cntw, p5);
    k_st0fin<<<1, 256, 0, stream>>>(p5, rpart, w0t, g0, be0, st0);
    k_conv1f<<<1024, 256, 0, stream>>>(F1, idx, relx, rely, relz, w0t, w1b, st0,
                                       bufA, part, partq);
    k_bnfin<<<128, 256, 0, stream>>>(part, partq, g1, be1, st1, 1024);
    k_conv2pool<<<1024, 256, 0, stream>>>(bufA, w2b, st1, rawmax, rawmin, part, partq);
    k_bnfin<<<256, 256, 0, stream>>>(part, partq, g2, be2, st2, 1024);
    k_final<<<4096, 256, 0, stream>>>(rawmax, rawmin, st2, out);
}